// Round 18
// baseline (230.300 us; speedup 1.0000x reference)
//
#include <hip/hip_runtime.h>
#include <hip/hip_bf16.h>

typedef __attribute__((ext_vector_type(4))) float f32x4;
typedef __attribute__((ext_vector_type(16))) float f32x16;
typedef __attribute__((ext_vector_type(8))) short s16x8;
typedef __attribute__((ext_vector_type(4))) unsigned int u32x4;

#define MFMA16(a, b, c) __builtin_amdgcn_mfma_f32_16x16x32_bf16(a, b, c, 0, 0, 0)
#define MFMA32(a, b, c) __builtin_amdgcn_mfma_f32_32x32x16_bf16(a, b, c, 0, 0, 0)

__device__ __forceinline__ short f2bf(float f) {
  unsigned u = __builtin_bit_cast(unsigned, f);
  u += 0x7fffu + ((u >> 16) & 1u);
  return (short)(u >> 16);
}
__device__ __forceinline__ float bf2f(unsigned short u) {
  return __builtin_bit_cast(float, ((unsigned)u) << 16);
}
__device__ __forceinline__ unsigned cvtpk(float lo, float hi) {
  unsigned r;
  asm("v_cvt_pk_bf16_f32 %0, %1, %2" : "=v"(r) : "v"(lo), "v"(hi));
  return r;
}
__device__ __forceinline__ float ex2(float x) {
  float r;
  asm("v_exp_f32 %0, %1" : "=v"(r) : "v"(x));
  return r;
}
// async global->LDS, 16B per lane; LDS dest = wave-uniform base + lane*16
__device__ __forceinline__ void gl_lds16(const unsigned short* g, short* l) {
  __builtin_amdgcn_global_load_lds(
      (const __attribute__((address_space(1))) unsigned int*)g,
      (__attribute__((address_space(3))) unsigned int*)l, 16, 0, 0);
}

// ---------------------------------------------------------------------------
// Pre-conversion kernels (validated r6-r17)
// ---------------------------------------------------------------------------
__global__ __launch_bounds__(256) void convert_x(
    const float* __restrict__ X, unsigned short* __restrict__ Xb) {
  const size_t i = ((size_t)blockIdx.x * 256 + threadIdx.x) * 8;
  f32x4 a = *(const f32x4*)(X + i);
  f32x4 b = *(const f32x4*)(X + i + 4);
  s16x8 o;
#pragma unroll
  for (int e = 0; e < 4; ++e) o[e] = f2bf(a[e]);
#pragma unroll
  for (int e = 0; e < 4; ++e) o[4 + e] = f2bf(b[e]);
  *(s16x8*)(Xb + i) = o;
}

__global__ __launch_bounds__(256) void tconv(
    const float* __restrict__ W, unsigned short* __restrict__ Wt,
    int K, int N) {
  __shared__ float T[64][65];
  const int k0 = blockIdx.x * 64, n0 = blockIdx.y * 64;
  const int t = threadIdx.x;
  const int tr = t >> 4, tc = (t & 15) * 4;
#pragma unroll
  for (int i = 0; i < 4; ++i) {
    f32x4 v = *(const f32x4*)&W[(size_t)(k0 + tr + i * 16) * N + n0 + tc];
#pragma unroll
    for (int e = 0; e < 4; ++e) T[tc + e][tr + i * 16] = v[e];
  }
  __syncthreads();
  const int nn = t >> 2, kk = (t & 3) * 16;
  s16x8 o0, o1;
#pragma unroll
  for (int j = 0; j < 8; ++j) o0[j] = f2bf(T[nn][kk + j]);
#pragma unroll
  for (int j = 0; j < 8; ++j) o1[j] = f2bf(T[nn][kk + 8 + j]);
  *(s16x8*)&Wt[(size_t)(n0 + nn) * K + k0 + kk] = o0;
  *(s16x8*)&Wt[(size_t)(n0 + nn) * K + k0 + kk + 8] = o1;
}

// ---------------------------------------------------------------------------
// GEMM tiles: 128x128, BK=32, 4 waves (2x2), global_load_lds staging.
// V store key-permuted (quad-swap within 16-token groups) — validated r12.
// ---------------------------------------------------------------------------
__global__ __launch_bounds__(256) void qkv_gemm(
    const unsigned short* __restrict__ Xb, const unsigned short* __restrict__ Wt,
    const float* __restrict__ bias, unsigned short* __restrict__ Qo,
    unsigned short* __restrict__ Ko, unsigned short* __restrict__ VTo) {
  __shared__ __align__(16) short As[128 * 32];
  __shared__ __align__(16) short Bs[128 * 32];
  const int m0 = blockIdx.x * 128, n0 = blockIdx.y * 128;
  const int tid = threadIdx.x, lane = tid & 63, wid = tid >> 6;
  const int wr = wid >> 1, wc = wid & 1;
  const int lr = lane & 15, s4 = lane >> 4;

  const int crow = lane >> 2;
  const int ccol = (lane & 3) ^ (crow & 3);
  const unsigned short* ga0 = Xb + (size_t)(m0 + wid * 32 + crow) * 768 + ccol * 8;
  const unsigned short* ga1 = ga0 + (size_t)16 * 768;
  const unsigned short* gb0 = Wt + (size_t)(n0 + wid * 32 + crow) * 768 + ccol * 8;
  const unsigned short* gb1 = gb0 + (size_t)16 * 768;
  short* lA0 = &As[(wid * 2) * 512];
  short* lA1 = &As[(wid * 2 + 1) * 512];
  short* lB0 = &Bs[(wid * 2) * 512];
  short* lB1 = &Bs[(wid * 2 + 1) * 512];

  f32x4 acc[4][4];
#pragma unroll
  for (int i = 0; i < 4; ++i)
#pragma unroll
    for (int j = 0; j < 4; ++j)
#pragma unroll
      for (int e = 0; e < 4; ++e) acc[i][j][e] = 0.f;

  for (int k0 = 0; k0 < 768; k0 += 32) {
    gl_lds16(ga0 + k0, lA0);
    gl_lds16(ga1 + k0, lA1);
    gl_lds16(gb0 + k0, lB0);
    gl_lds16(gb1 + k0, lB1);
    __syncthreads();
    s16x8 af[4], bfr[4];
#pragma unroll
    for (int mi = 0; mi < 4; ++mi) {
      const int row = wr * 64 + mi * 16 + lr;
      af[mi] = *(const s16x8*)&As[row * 32 + ((s4 ^ (row & 3)) << 3)];
    }
#pragma unroll
    for (int ni = 0; ni < 4; ++ni) {
      const int row = wc * 64 + ni * 16 + lr;
      bfr[ni] = *(const s16x8*)&Bs[row * 32 + ((s4 ^ (row & 3)) << 3)];
    }
#pragma unroll
    for (int mi = 0; mi < 4; ++mi)
#pragma unroll
      for (int ni = 0; ni < 4; ++ni)
        acc[mi][ni] = MFMA16(af[mi], bfr[ni], acc[mi][ni]);
    __syncthreads();
  }

  const float QSC = 0.18033688011f;  // 0.125 * log2(e)
  const int lg = lane >> 4;
  const int plg = ((lg & 1) << 1) | ((lg >> 1) & 1);  // quad swap 1<->2
  const int rbase = m0 + wr * 64 + lg * 4;
#pragma unroll
  for (int ni = 0; ni < 4; ++ni) {
    const int cb = n0 + wc * 64 + ni * 16;
    const int which = cb / 768;
    const int rem = cb - which * 768;
    const int h = rem >> 6;
    const int d = (rem & 63) + lr;
    const float bi = bias[cb + lr];
#pragma unroll
    for (int mi = 0; mi < 4; ++mi) {
#pragma unroll
      for (int j = 0; j < 4; ++j) {
        const int row = rbase + mi * 16 + j;
        const int bb = row >> 12, t = row & 4095;
        const float v = acc[mi][ni][j] + bi;
        const size_t hb = (size_t)(bb * 12 + h);
        if (which == 0)
          Qo[(hb * 4096 + t) * 64 + d] = (unsigned short)f2bf(v * QSC);
        else if (which == 1)
          Ko[(hb * 4096 + t) * 64 + d] = (unsigned short)f2bf(v);
        else {
          const int tp = (t & ~15) + plg * 4 + j;  // key-permuted token slot
          VTo[(hb * 64 + d) * 4096 + tp] = (unsigned short)f2bf(v);
        }
      }
    }
  }
}

// ---------------------------------------------------------------------------
// Flash attention r18 (= r17 validated body, KV-split 2 -> 4):
// dual-q-subtile 64 q/wave, gl_lds staging, VALU lsum tree, bf16 partials,
// XCD-aware swizzle. 1536 blocks -> 4 blocks/CU resident (16 waves/CU).
// ---------------------------------------------------------------------------
#define TKV 16  // 64 tiles / 4 splits

__global__ __launch_bounds__(256) void attn_fwd(
    const unsigned short* __restrict__ Qg, const unsigned short* __restrict__ Kg,
    const unsigned short* __restrict__ VTg,
    unsigned short* __restrict__ Opart, float* __restrict__ Lpart) {
  __shared__ __align__(16) short smem[16384];  // [K0|K1|V0|V1] 4096 shorts each
  // XCD swizzle: 1536 = 8*192, bijective. Each XCD gets 192 consecutive wg
  // = 12 bh x one KV quarter (~3 MB) -> fits 4 MB per-XCD L2.
  const int lin = blockIdx.x;
  const int wg = (lin & 7) * 192 + (lin >> 3);
  const int qt = wg & 15, bh = (wg >> 4) % 24, sz = wg / 384;
  const int tok0 = sz * TKV * 64;
  const unsigned short* Qh = Qg + (size_t)bh * 4096 * 64;
  const unsigned short* Kh = Kg + (size_t)bh * 4096 * 64;
  const unsigned short* Vh = VTg + (size_t)bh * 4096 * 64;  // [d][tok], permuted
  const int tid = threadIdx.x, lane = tid & 63, wid = tid >> 6;
  const int l31 = lane & 31, hi = lane >> 5;
  const int sw0 = (l31 + (l31 >> 3)) & 7;
  const int sw1 = (sw0 + 4) & 7;
  const int qbase = qt * 256 + wid * 64;

  s16x8 qfA[4], qfB[4];
#pragma unroll
  for (int db = 0; db < 4; ++db) {
    qfA[db] = *(const s16x8*)&Qh[(size_t)(qbase + l31) * 64 + db * 16 + hi * 8];
    qfB[db] = *(const s16x8*)&Qh[(size_t)(qbase + 32 + l31) * 64 + db * 16 + hi * 8];
  }

  f32x16 zf;
#pragma unroll
  for (int r = 0; r < 16; ++r) zf[r] = 0.f;
  f32x16 oA0 = zf, oA1 = zf, oB0 = zf, oB1 = zf;
  float lsumA = 0.f, lsumB = 0.f;

  // gl_lds staging geometry (r12): wave w covers LDS rows w*16 + e*8 + (lane>>3),
  // slot c16 = lane&7; swizzle folded into per-lane GLOBAL source address.
  const int r0 = wid * 16 + (lane >> 3);
  const int r1 = r0 + 8;
  const int c16 = lane & 7;
  const int sc0 = (c16 ^ ((r0 + (r0 >> 3)) & 7)) << 3;
  const int sc1 = (c16 ^ ((r1 + (r1 >> 3)) & 7)) << 3;
  const unsigned short* kg0 = Kh + (size_t)(tok0 + r0) * 64 + sc0;  // + t*4096
  const unsigned short* kg1 = Kh + (size_t)(tok0 + r1) * 64 + sc1;
  const unsigned short* vg0 = Vh + (size_t)r0 * 4096 + tok0 + sc0;  // + t*64
  const unsigned short* vg1 = Vh + (size_t)r1 * 4096 + tok0 + sc1;
  short* const ldsK0 = &smem[(wid * 2) * 512];
  short* const ldsK1 = &smem[(wid * 2 + 1) * 512];
  short* const ldsV0 = &smem[8192 + (wid * 2) * 512];
  short* const ldsV1 = &smem[8192 + (wid * 2 + 1) * 512];

  // prologue: stage tile 0 into buffer 0
  gl_lds16(kg0, ldsK0);
  gl_lds16(kg1, ldsK1);
  gl_lds16(vg0, ldsV0);
  gl_lds16(vg1, ldsV1);
  __syncthreads();

#define PACK_PF(pfv, sv, bse)                                           \
  {                                                                     \
    u32x4 fw;                                                           \
    fw[0] = cvtpk(sv[bse + 0], sv[bse + 1]);                            \
    fw[1] = cvtpk(sv[bse + 2], sv[bse + 3]);                            \
    fw[2] = cvtpk(sv[bse + 4], sv[bse + 5]);                            \
    fw[3] = cvtpk(sv[bse + 6], sv[bse + 7]);                            \
    pfv = __builtin_bit_cast(s16x8, fw);                                \
  }
#define LSUM_TREE(lsum, sv)                                             \
  {                                                                     \
    float ta[8];                                                        \
    _Pragma("unroll") for (int r = 0; r < 8; ++r) ta[r] = sv[r] + sv[r + 8]; \
    _Pragma("unroll") for (int off = 4; off; off >>= 1)                 \
      _Pragma("unroll") for (int r = 0; r < off; ++r) ta[r] += ta[r + off]; \
    lsum += ta[0];                                                      \
  }

  int cur = 0;
  for (int t = 0; t < TKV; ++t) {
    if (t < TKV - 1) {  // async prefetch tile t+1 into other buffer
      const int nb = (cur ^ 1) * 4096;
      gl_lds16(kg0 + (size_t)(t + 1) * 4096, ldsK0 + nb);
      gl_lds16(kg1 + (size_t)(t + 1) * 4096, ldsK1 + nb);
      gl_lds16(vg0 + (t + 1) * 64, ldsV0 + nb);
      gl_lds16(vg1 + (t + 1) * 64, ldsV1 + nb);
    }
    const short* Kc = smem + cur * 4096;
    const short* Vc = smem + 8192 + cur * 4096;

    // ---- keys 0..31 (K rows l31) ----
    {
      f32x16 sA = zf, sB = zf;
      __builtin_amdgcn_s_setprio(1);
#pragma unroll
      for (int db = 0; db < 4; ++db) {
        s16x8 kf = *(const s16x8*)&Kc[l31 * 64 + (((db * 2 + hi) ^ sw0) << 3)];
        sA = MFMA32(kf, qfA[db], sA);
        sB = MFMA32(kf, qfB[db], sB);
      }
      __builtin_amdgcn_s_setprio(0);
#pragma unroll
      for (int r = 0; r < 16; ++r) {
        sA[r] = ex2(sA[r]);
        sB[r] = ex2(sB[r]);
      }
      s16x8 pfA0, pfA1, pfB0, pfB1;
      PACK_PF(pfA0, sA, 0)
      PACK_PF(pfA1, sA, 8)
      PACK_PF(pfB0, sB, 0)
      PACK_PF(pfB1, sB, 8)
      LSUM_TREE(lsumA, sA)
      LSUM_TREE(lsumB, sB)
      __builtin_amdgcn_s_setprio(1);
      s16x8 v0 = *(const s16x8*)&Vc[l31 * 64 + (((0 + hi) ^ sw0) << 3)];
      s16x8 v1 = *(const s16x8*)&Vc[l31 * 64 + (((2 + hi) ^ sw0) << 3)];
      s16x8 w0 = *(const s16x8*)&Vc[(32 + l31) * 64 + (((0 + hi) ^ sw1) << 3)];
      s16x8 w1 = *(const s16x8*)&Vc[(32 + l31) * 64 + (((2 + hi) ^ sw1) << 3)];
      oA0 = MFMA32(v0, pfA0, oA0);
      oA0 = MFMA32(v1, pfA1, oA0);
      oA1 = MFMA32(w0, pfA0, oA1);
      oA1 = MFMA32(w1, pfA1, oA1);
      oB0 = MFMA32(v0, pfB0, oB0);
      oB0 = MFMA32(v1, pfB1, oB0);
      oB1 = MFMA32(w0, pfB0, oB1);
      oB1 = MFMA32(w1, pfB1, oB1);
      __builtin_amdgcn_s_setprio(0);
    }

    // ---- keys 32..63 (K rows 32+l31) ----
    {
      f32x16 sA = zf, sB = zf;
      __builtin_amdgcn_s_setprio(1);
#pragma unroll
      for (int db = 0; db < 4; ++db) {
        s16x8 kf = *(const s16x8*)&Kc[(32 + l31) * 64 + (((db * 2 + hi) ^ sw1) << 3)];
        sA = MFMA32(kf, qfA[db], sA);
        sB = MFMA32(kf, qfB[db], sB);
      }
      __builtin_amdgcn_s_setprio(0);
#pragma unroll
      for (int r = 0; r < 16; ++r) {
        sA[r] = ex2(sA[r]);
        sB[r] = ex2(sB[r]);
      }
      s16x8 pfA2, pfA3, pfB2, pfB3;
      PACK_PF(pfA2, sA, 0)
      PACK_PF(pfA3, sA, 8)
      PACK_PF(pfB2, sB, 0)
      PACK_PF(pfB3, sB, 8)
      LSUM_TREE(lsumA, sA)
      LSUM_TREE(lsumB, sB)
      __builtin_amdgcn_s_setprio(1);
      s16x8 v2 = *(const s16x8*)&Vc[l31 * 64 + (((4 + hi) ^ sw0) << 3)];
      s16x8 v3 = *(const s16x8*)&Vc[l31 * 64 + (((6 + hi) ^ sw0) << 3)];
      s16x8 w2 = *(const s16x8*)&Vc[(32 + l31) * 64 + (((4 + hi) ^ sw1) << 3)];
      s16x8 w3 = *(const s16x8*)&Vc[(32 + l31) * 64 + (((6 + hi) ^ sw1) << 3)];
      oA0 = MFMA32(v2, pfA2, oA0);
      oA0 = MFMA32(v3, pfA3, oA0);
      oA1 = MFMA32(w2, pfA2, oA1);
      oA1 = MFMA32(w3, pfA3, oA1);
      oB0 = MFMA32(v2, pfB2, oB0);
      oB0 = MFMA32(v3, pfB3, oB0);
      oB1 = MFMA32(w2, pfB2, oB1);
      oB1 = MFMA32(w3, pfB3, oB1);
      __builtin_amdgcn_s_setprio(0);
    }

    if (t < TKV - 1) {
      __syncthreads();  // drains vmcnt -> tile t+1 resident
      cur ^= 1;
    }
  }
#undef LSUM_TREE
#undef PACK_PF

  // bf16 partials: Opart[sz][bh][d][4096], Lpart[sz][bh][4096]
  const float lfullA = lsumA + __shfl_xor(lsumA, 32);
  const float lfullB = lsumB + __shfl_xor(lsumB, 32);
  const int qA = qbase + l31, qB = qbase + 32 + l31;
  const size_t ob = ((size_t)(sz * 24 + bh)) * 64 * 4096;
#pragma unroll
  for (int r = 0; r < 16; ++r) {
    const int dd = (r & 3) + 8 * (r >> 2) + 4 * hi;
    Opart[ob + (size_t)dd * 4096 + qA] = (unsigned short)f2bf(oA0[r]);
    Opart[ob + (size_t)(dd + 32) * 4096 + qA] = (unsigned short)f2bf(oA1[r]);
    Opart[ob + (size_t)dd * 4096 + qB] = (unsigned short)f2bf(oB0[r]);
    Opart[ob + (size_t)(dd + 32) * 4096 + qB] = (unsigned short)f2bf(oB1[r]);
  }
  Lpart[(size_t)(sz * 24 + bh) * 4096 + qA] = lfullA;
  Lpart[(size_t)(sz * 24 + bh) * 4096 + qB] = lfullB;
}

// Combine: O = sum_s Opart (bf16, 4 splits), l = sum_s Lpart; normalize;
// transpose -> bf16
__global__ __launch_bounds__(256) void attn_combine(
    const unsigned short* __restrict__ Opart, const float* __restrict__ Lpart,
    unsigned short* __restrict__ Aout) {
  __shared__ float T[64][65];
  const int q0 = blockIdx.x * 64, bh = blockIdx.y;
  const int t = threadIdx.x;
  const int d = t >> 2, qc = (t & 3) * 16;
  const size_t stride = (size_t)24 * 64 * 4096;
  const size_t b0 = ((size_t)bh * 64 + d) * 4096 + q0 + qc;
  float acc[16];
#pragma unroll
  for (int e = 0; e < 16; ++e) acc[e] = 0.f;
#pragma unroll
  for (int s = 0; s < 4; ++s) {
    s16x8 a0 = *(const s16x8*)&Opart[b0 + s * stride];
    s16x8 a1 = *(const s16x8*)&Opart[b0 + s * stride + 8];
#pragma unroll
    for (int e = 0; e < 8; ++e) {
      acc[e] += bf2f((unsigned short)a0[e]);
      acc[8 + e] += bf2f((unsigned short)a1[e]);
    }
  }
#pragma unroll
  for (int e = 0; e < 16; ++e) T[qc + e][d] = acc[e];
  __syncthreads();
  const int q = t >> 2, dc = (t & 3) * 16;
  float l = 0.f;
#pragma unroll
  for (int s = 0; s < 4; ++s)
    l += Lpart[(size_t)(s * 24 + bh) * 4096 + q0 + q];
  const float inv = 1.0f / l;
  const int b = bh / 12, h = bh - b * 12;
  s16x8 o0, o1;
#pragma unroll
  for (int e = 0; e < 8; ++e) o0[e] = f2bf(T[q][dc + e] * inv);
#pragma unroll
  for (int e = 0; e < 8; ++e) o1[e] = f2bf(T[q][dc + 8 + e] * inv);
  const size_t gb = ((size_t)(b * 4096 + q0 + q)) * 768 + h * 64 + dc;
  *(s16x8*)&Aout[gb] = o0;
  *(s16x8*)&Aout[gb + 8] = o1;
}

// ---------------------------------------------------------------------------
// out = attn @ W_proj + b_proj  (global_load_lds staging, validated r9)
// ---------------------------------------------------------------------------
__global__ __launch_bounds__(256) void proj_gemm(
    const unsigned short* __restrict__ A, const unsigned short* __restrict__ Wt,
    const float* __restrict__ bias, float* __restrict__ out) {
  __shared__ __align__(16) short As[128 * 32];
  __shared__ __align__(16) short Bs[128 * 32];
  const int m0 = blockIdx.x * 128, n0 = blockIdx.y * 128;
  const int tid = threadIdx.x, lane = tid & 63, wid = tid >> 6;
  const int wr = wid >> 1, wc = wid & 1;
  const int lr = lane & 15, s4 = lane >> 4;

  const int crow = lane >> 2;
  const int ccol = (lane & 3) ^ (crow & 3);
  const unsigned short* ga0 = A + (size_t)(m0 + wid * 32 + crow) * 768 + ccol * 8;
  const unsigned short* ga1 = ga0 + (size_t)16 * 768;
  const unsigned short* gb0 = Wt + (size_t)(n0 + wid * 32 + crow) * 768 + ccol * 8;
  const unsigned short* gb1 = gb0 + (size_t)16 * 768;
  short* lA0 = &As[(wid * 2) * 512];
  short* lA1 = &As[(wid * 2 + 1) * 512];
  short* lB0 = &Bs[(wid * 2) * 512];
  short* lB1 = &Bs[(wid * 2 + 1) * 512];

  f32x4 acc[4][4];
#pragma unroll
  for (int i = 0; i < 4; ++i)
#pragma unroll
    for (int j = 0; j < 4; ++j)
#pragma unroll
      for (int e = 0; e < 4; ++e) acc[i][j][e] = 0.f;

  for (int k0 = 0; k0 < 768; k0 += 32) {
    gl_lds16(ga0 + k0, lA0);
    gl_lds16(ga1 + k0, lA1);
    gl_lds16(gb0 + k0, lB0);
    gl_lds16(gb1 + k0, lB1);
    __syncthreads();
    s16x8 af[4], bfr[4];
#pragma unroll
    for (int mi = 0; mi < 4; ++mi) {
      const int row = wr * 64 + mi * 16 + lr;
      af[mi] = *(const s16x8*)&As[row * 32 + ((s4 ^ (row & 3)) << 3)];
    }
#pragma unroll
    for (int ni = 0; ni < 4; ++ni) {
      const int row = wc * 64 + ni * 16 + lr;
      bfr[ni] = *(const s16x8*)&Bs[row * 32 + ((s4 ^ (row & 3)) << 3)];
    }
#pragma unroll
    for (int mi = 0; mi < 4; ++mi)
#pragma unroll
      for (int ni = 0; ni < 4; ++ni)
        acc[mi][ni] = MFMA16(af[mi], bfr[ni], acc[mi][ni]);
    __syncthreads();
  }

  const int rbase = m0 + wr * 64 + (lane >> 4) * 4;
#pragma unroll
  for (int ni = 0; ni < 4; ++ni) {
    const int cb = n0 + wc * 64 + ni * 16;
    const float bi = bias[cb + lr];
#pragma unroll
    for (int mi = 0; mi < 4; ++mi) {
#pragma unroll
      for (int j = 0; j < 4; ++j) {
        const int row = rbase + mi * 16 + j;
        out[(size_t)row * 768 + cb + lr] = acc[mi][ni][j] + bi;
      }
    }
  }
}

extern "C" void kernel_launch(void* const* d_in, const int* in_sizes, int n_in,
                              void* d_out, int out_size, void* d_ws, size_t ws_size,
                              hipStream_t stream) {
  const float* x = (const float*)d_in[0];
  const float* W_qkv = (const float*)d_in[1];
  const float* b_qkv = (const float*)d_in[2];
  const float* W_proj = (const float*)d_in[3];
  const float* b_proj = (const float*)d_in[4];
  float* out = (float*)d_out;

  unsigned short* ws = (unsigned short*)d_ws;
  const size_t NQ = (size_t)24 * 4096 * 64;
  unsigned short* q = ws;
  unsigned short* k = ws + NQ;
  unsigned short* vt = ws + 2 * NQ;
  unsigned short* xb_attn = ws + 3 * NQ;  // Xb bf16, later attn out (aliased)
  unsigned short* wqt = ws + 4 * NQ;
  unsigned short* wpt = wqt + (size_t)2304 * 768;

  const size_t base_bytes = (4 * NQ + (size_t)2304 * 768 + (size_t)768 * 768) * 2;
  // Opart bf16 split-4: 4*24*64*4096*2 B = 50.3 MB (fits proven ws envelope)
  unsigned short* Opart = (unsigned short*)((char*)d_ws + base_bytes);
  // Lpart (1.6 MB) aliased onto wqt (3.5 MB) — wqt is dead after qkv_gemm,
  // and attn_fwd (writer of Lpart) runs strictly after qkv_gemm.
  float* Lpart = (float*)wqt;

  convert_x<<<3072, 256, 0, stream>>>(x, xb_attn);
  tconv<<<dim3(12, 36), 256, 0, stream>>>(W_qkv, wqt, 768, 2304);
  tconv<<<dim3(12, 12), 256, 0, stream>>>(W_proj, wpt, 768, 768);
  qkv_gemm<<<dim3(64, 18), 256, 0, stream>>>(xb_attn, wqt, b_qkv, q, k, vt);
  attn_fwd<<<1536, 256, 0, stream>>>(q, k, vt, Opart, Lpart);
  attn_combine<<<dim3(64, 24), 256, 0, stream>>>(Opart, Lpart, xb_attn);
  proj_gemm<<<dim3(64, 6), 256, 0, stream>>>(xb_attn, wpt, b_proj, out);
}

// Round 19
// 226.971 us; speedup vs baseline: 1.0147x; 1.0147x over previous
//
#include <hip/hip_runtime.h>
#include <hip/hip_bf16.h>

typedef __attribute__((ext_vector_type(4))) float f32x4;
typedef __attribute__((ext_vector_type(16))) float f32x16;
typedef __attribute__((ext_vector_type(8))) short s16x8;
typedef __attribute__((ext_vector_type(4))) unsigned int u32x4;

#define MFMA16(a, b, c) __builtin_amdgcn_mfma_f32_16x16x32_bf16(a, b, c, 0, 0, 0)
#define MFMA32(a, b, c) __builtin_amdgcn_mfma_f32_32x32x16_bf16(a, b, c, 0, 0, 0)

__device__ __forceinline__ short f2bf(float f) {
  unsigned u = __builtin_bit_cast(unsigned, f);
  u += 0x7fffu + ((u >> 16) & 1u);
  return (short)(u >> 16);
}
__device__ __forceinline__ float bf2f(unsigned short u) {
  return __builtin_bit_cast(float, ((unsigned)u) << 16);
}
__device__ __forceinline__ unsigned cvtpk(float lo, float hi) {
  unsigned r;
  asm("v_cvt_pk_bf16_f32 %0, %1, %2" : "=v"(r) : "v"(lo), "v"(hi));
  return r;
}
__device__ __forceinline__ float ex2(float x) {
  float r;
  asm("v_exp_f32 %0, %1" : "=v"(r) : "v"(x));
  return r;
}
// async global->LDS, 16B per lane; LDS dest = wave-uniform base + lane*16
__device__ __forceinline__ void gl_lds16(const unsigned short* g, short* l) {
  __builtin_amdgcn_global_load_lds(
      (const __attribute__((address_space(1))) unsigned int*)g,
      (__attribute__((address_space(3))) unsigned int*)l, 16, 0, 0);
}

// ---------------------------------------------------------------------------
// Pre-conversion kernels (validated r6-r18)
// ---------------------------------------------------------------------------
__global__ __launch_bounds__(256) void convert_x(
    const float* __restrict__ X, unsigned short* __restrict__ Xb) {
  const size_t i = ((size_t)blockIdx.x * 256 + threadIdx.x) * 8;
  f32x4 a = *(const f32x4*)(X + i);
  f32x4 b = *(const f32x4*)(X + i + 4);
  s16x8 o;
#pragma unroll
  for (int e = 0; e < 4; ++e) o[e] = f2bf(a[e]);
#pragma unroll
  for (int e = 0; e < 4; ++e) o[4 + e] = f2bf(b[e]);
  *(s16x8*)(Xb + i) = o;
}

__global__ __launch_bounds__(256) void tconv(
    const float* __restrict__ W, unsigned short* __restrict__ Wt,
    int K, int N) {
  __shared__ float T[64][65];
  const int k0 = blockIdx.x * 64, n0 = blockIdx.y * 64;
  const int t = threadIdx.x;
  const int tr = t >> 4, tc = (t & 15) * 4;
#pragma unroll
  for (int i = 0; i < 4; ++i) {
    f32x4 v = *(const f32x4*)&W[(size_t)(k0 + tr + i * 16) * N + n0 + tc];
#pragma unroll
    for (int e = 0; e < 4; ++e) T[tc + e][tr + i * 16] = v[e];
  }
  __syncthreads();
  const int nn = t >> 2, kk = (t & 3) * 16;
  s16x8 o0, o1;
#pragma unroll
  for (int j = 0; j < 8; ++j) o0[j] = f2bf(T[nn][kk + j]);
#pragma unroll
  for (int j = 0; j < 8; ++j) o1[j] = f2bf(T[nn][kk + 8 + j]);
  *(s16x8*)&Wt[(size_t)(n0 + nn) * K + k0 + kk] = o0;
  *(s16x8*)&Wt[(size_t)(n0 + nn) * K + k0 + kk + 8] = o1;
}

// ---------------------------------------------------------------------------
// GEMM tiles: 128x128, BK=32, 4 waves (2x2), global_load_lds staging.
// V store key-permuted (quad-swap within 16-token groups) — validated r12.
// ---------------------------------------------------------------------------
__global__ __launch_bounds__(256) void qkv_gemm(
    const unsigned short* __restrict__ Xb, const unsigned short* __restrict__ Wt,
    const float* __restrict__ bias, unsigned short* __restrict__ Qo,
    unsigned short* __restrict__ Ko, unsigned short* __restrict__ VTo) {
  __shared__ __align__(16) short As[128 * 32];
  __shared__ __align__(16) short Bs[128 * 32];
  const int m0 = blockIdx.x * 128, n0 = blockIdx.y * 128;
  const int tid = threadIdx.x, lane = tid & 63, wid = tid >> 6;
  const int wr = wid >> 1, wc = wid & 1;
  const int lr = lane & 15, s4 = lane >> 4;

  const int crow = lane >> 2;
  const int ccol = (lane & 3) ^ (crow & 3);
  const unsigned short* ga0 = Xb + (size_t)(m0 + wid * 32 + crow) * 768 + ccol * 8;
  const unsigned short* ga1 = ga0 + (size_t)16 * 768;
  const unsigned short* gb0 = Wt + (size_t)(n0 + wid * 32 + crow) * 768 + ccol * 8;
  const unsigned short* gb1 = gb0 + (size_t)16 * 768;
  short* lA0 = &As[(wid * 2) * 512];
  short* lA1 = &As[(wid * 2 + 1) * 512];
  short* lB0 = &Bs[(wid * 2) * 512];
  short* lB1 = &Bs[(wid * 2 + 1) * 512];

  f32x4 acc[4][4];
#pragma unroll
  for (int i = 0; i < 4; ++i)
#pragma unroll
    for (int j = 0; j < 4; ++j)
#pragma unroll
      for (int e = 0; e < 4; ++e) acc[i][j][e] = 0.f;

  for (int k0 = 0; k0 < 768; k0 += 32) {
    gl_lds16(ga0 + k0, lA0);
    gl_lds16(ga1 + k0, lA1);
    gl_lds16(gb0 + k0, lB0);
    gl_lds16(gb1 + k0, lB1);
    __syncthreads();
    s16x8 af[4], bfr[4];
#pragma unroll
    for (int mi = 0; mi < 4; ++mi) {
      const int row = wr * 64 + mi * 16 + lr;
      af[mi] = *(const s16x8*)&As[row * 32 + ((s4 ^ (row & 3)) << 3)];
    }
#pragma unroll
    for (int ni = 0; ni < 4; ++ni) {
      const int row = wc * 64 + ni * 16 + lr;
      bfr[ni] = *(const s16x8*)&Bs[row * 32 + ((s4 ^ (row & 3)) << 3)];
    }
#pragma unroll
    for (int mi = 0; mi < 4; ++mi)
#pragma unroll
      for (int ni = 0; ni < 4; ++ni)
        acc[mi][ni] = MFMA16(af[mi], bfr[ni], acc[mi][ni]);
    __syncthreads();
  }

  const float QSC = 0.18033688011f;  // 0.125 * log2(e)
  const int lg = lane >> 4;
  const int plg = ((lg & 1) << 1) | ((lg >> 1) & 1);  // quad swap 1<->2
  const int rbase = m0 + wr * 64 + lg * 4;
#pragma unroll
  for (int ni = 0; ni < 4; ++ni) {
    const int cb = n0 + wc * 64 + ni * 16;
    const int which = cb / 768;
    const int rem = cb - which * 768;
    const int h = rem >> 6;
    const int d = (rem & 63) + lr;
    const float bi = bias[cb + lr];
#pragma unroll
    for (int mi = 0; mi < 4; ++mi) {
#pragma unroll
      for (int j = 0; j < 4; ++j) {
        const int row = rbase + mi * 16 + j;
        const int bb = row >> 12, t = row & 4095;
        const float v = acc[mi][ni][j] + bi;
        const size_t hb = (size_t)(bb * 12 + h);
        if (which == 0)
          Qo[(hb * 4096 + t) * 64 + d] = (unsigned short)f2bf(v * QSC);
        else if (which == 1)
          Ko[(hb * 4096 + t) * 64 + d] = (unsigned short)f2bf(v);
        else {
          const int tp = (t & ~15) + plg * 4 + j;  // key-permuted token slot
          VTo[(hb * 64 + d) * 4096 + tp] = (unsigned short)f2bf(v);
        }
      }
    }
  }
}

// ---------------------------------------------------------------------------
// Flash attention r19 (= r17 validated body + T4 depth-2 pipeline):
// dual-q-subtile 64 q/wave, gl_lds staging, VALU lsum tree, KV-split-2,
// bf16 partials, XCD swizzle. Triple-buffered K/V; per-tile sync is
// counted `s_waitcnt vmcnt(4)` + raw s_barrier (t+2 loads stay in flight)
// instead of __syncthreads' vmcnt(0) drain.
// ---------------------------------------------------------------------------
#define TKV 32

__global__ __launch_bounds__(256) void attn_fwd(
    const unsigned short* __restrict__ Qg, const unsigned short* __restrict__ Kg,
    const unsigned short* __restrict__ VTg,
    unsigned short* __restrict__ Opart, float* __restrict__ Lpart) {
  __shared__ __align__(16) short smem[24576];  // K0|K1|K2|V0|V1|V2 (4096 each)
  // XCD swizzle: 768 = 8*96, bijective (r17-validated).
  const int lin = blockIdx.x;
  const int wg = (lin & 7) * 96 + (lin >> 3);
  const int qt = wg & 15, bh = (wg >> 4) % 24, sz = wg / 384;
  const int tok0 = sz * TKV * 64;
  const unsigned short* Qh = Qg + (size_t)bh * 4096 * 64;
  const unsigned short* Kh = Kg + (size_t)bh * 4096 * 64;
  const unsigned short* Vh = VTg + (size_t)bh * 4096 * 64;  // [d][tok], permuted
  const int tid = threadIdx.x, lane = tid & 63, wid = tid >> 6;
  const int l31 = lane & 31, hi = lane >> 5;
  const int sw0 = (l31 + (l31 >> 3)) & 7;
  const int sw1 = (sw0 + 4) & 7;
  const int qbase = qt * 256 + wid * 64;

  s16x8 qfA[4], qfB[4];
#pragma unroll
  for (int db = 0; db < 4; ++db) {
    qfA[db] = *(const s16x8*)&Qh[(size_t)(qbase + l31) * 64 + db * 16 + hi * 8];
    qfB[db] = *(const s16x8*)&Qh[(size_t)(qbase + 32 + l31) * 64 + db * 16 + hi * 8];
  }

  f32x16 zf;
#pragma unroll
  for (int r = 0; r < 16; ++r) zf[r] = 0.f;
  f32x16 oA0 = zf, oA1 = zf, oB0 = zf, oB1 = zf;
  float lsumA = 0.f, lsumB = 0.f;

  // gl_lds staging geometry (r12): wave w covers LDS rows w*16 + e*8 + (lane>>3),
  // slot c16 = lane&7; swizzle folded into per-lane GLOBAL source address.
  const int r0 = wid * 16 + (lane >> 3);
  const int r1 = r0 + 8;
  const int c16 = lane & 7;
  const int sc0 = (c16 ^ ((r0 + (r0 >> 3)) & 7)) << 3;
  const int sc1 = (c16 ^ ((r1 + (r1 >> 3)) & 7)) << 3;
  const unsigned short* kg0 = Kh + (size_t)(tok0 + r0) * 64 + sc0;  // + t*4096
  const unsigned short* kg1 = Kh + (size_t)(tok0 + r1) * 64 + sc1;
  const unsigned short* vg0 = Vh + (size_t)r0 * 4096 + tok0 + sc0;  // + t*64
  const unsigned short* vg1 = Vh + (size_t)r1 * 4096 + tok0 + sc1;
  const int wofs0 = (wid * 2) * 512, wofs1 = (wid * 2 + 1) * 512;

  // prologue: stage tile 0 -> slot 0, tile 1 -> slot 1 (8 loads in flight)
  gl_lds16(kg0, &smem[wofs0]);
  gl_lds16(kg1, &smem[wofs1]);
  gl_lds16(vg0, &smem[12288 + wofs0]);
  gl_lds16(vg1, &smem[12288 + wofs1]);
  gl_lds16(kg0 + 4096, &smem[4096 + wofs0]);
  gl_lds16(kg1 + 4096, &smem[4096 + wofs1]);
  gl_lds16(vg0 + 64, &smem[12288 + 4096 + wofs0]);
  gl_lds16(vg1 + 64, &smem[12288 + 4096 + wofs1]);
  asm volatile("s_waitcnt vmcnt(4)" ::: "memory");  // tile 0 resident
  __builtin_amdgcn_s_barrier();
  __builtin_amdgcn_sched_barrier(0);

#define PACK_PF(pfv, sv, bse)                                           \
  {                                                                     \
    u32x4 fw;                                                           \
    fw[0] = cvtpk(sv[bse + 0], sv[bse + 1]);                            \
    fw[1] = cvtpk(sv[bse + 2], sv[bse + 3]);                            \
    fw[2] = cvtpk(sv[bse + 4], sv[bse + 5]);                            \
    fw[3] = cvtpk(sv[bse + 6], sv[bse + 7]);                            \
    pfv = __builtin_bit_cast(s16x8, fw);                                \
  }
#define LSUM_TREE(lsum, sv)                                             \
  {                                                                     \
    float ta[8];                                                        \
    _Pragma("unroll") for (int r = 0; r < 8; ++r) ta[r] = sv[r] + sv[r + 8]; \
    _Pragma("unroll") for (int off = 4; off; off >>= 1)                 \
      _Pragma("unroll") for (int r = 0; r < off; ++r) ta[r] += ta[r + off]; \
    lsum += ta[0];                                                      \
  }

  int oc = 0, on = 4096, of = 8192;  // rotating slot offsets (cur/next/future)
  for (int t = 0; t < TKV; ++t) {
    if (t + 2 < TKV) {  // issue tile t+2 into 'future' slot; stays in flight
      gl_lds16(kg0 + (size_t)(t + 2) * 4096, &smem[of + wofs0]);
      gl_lds16(kg1 + (size_t)(t + 2) * 4096, &smem[of + wofs1]);
      gl_lds16(vg0 + (t + 2) * 64, &smem[12288 + of + wofs0]);
      gl_lds16(vg1 + (t + 2) * 64, &smem[12288 + of + wofs1]);
    }
    const short* Kc = smem + oc;
    const short* Vc = smem + 12288 + oc;

    // ---- keys 0..31 (K rows l31) ----
    {
      f32x16 sA = zf, sB = zf;
      __builtin_amdgcn_s_setprio(1);
#pragma unroll
      for (int db = 0; db < 4; ++db) {
        s16x8 kf = *(const s16x8*)&Kc[l31 * 64 + (((db * 2 + hi) ^ sw0) << 3)];
        sA = MFMA32(kf, qfA[db], sA);
        sB = MFMA32(kf, qfB[db], sB);
      }
      __builtin_amdgcn_s_setprio(0);
#pragma unroll
      for (int r = 0; r < 16; ++r) {
        sA[r] = ex2(sA[r]);
        sB[r] = ex2(sB[r]);
      }
      s16x8 pfA0, pfA1, pfB0, pfB1;
      PACK_PF(pfA0, sA, 0)
      PACK_PF(pfA1, sA, 8)
      PACK_PF(pfB0, sB, 0)
      PACK_PF(pfB1, sB, 8)
      LSUM_TREE(lsumA, sA)
      LSUM_TREE(lsumB, sB)
      __builtin_amdgcn_s_setprio(1);
      s16x8 v0 = *(const s16x8*)&Vc[l31 * 64 + (((0 + hi) ^ sw0) << 3)];
      s16x8 v1 = *(const s16x8*)&Vc[l31 * 64 + (((2 + hi) ^ sw0) << 3)];
      s16x8 w0 = *(const s16x8*)&Vc[(32 + l31) * 64 + (((0 + hi) ^ sw1) << 3)];
      s16x8 w1 = *(const s16x8*)&Vc[(32 + l31) * 64 + (((2 + hi) ^ sw1) << 3)];
      oA0 = MFMA32(v0, pfA0, oA0);
      oA0 = MFMA32(v1, pfA1, oA0);
      oA1 = MFMA32(w0, pfA0, oA1);
      oA1 = MFMA32(w1, pfA1, oA1);
      oB0 = MFMA32(v0, pfB0, oB0);
      oB0 = MFMA32(v1, pfB1, oB0);
      oB1 = MFMA32(w0, pfB0, oB1);
      oB1 = MFMA32(w1, pfB1, oB1);
      __builtin_amdgcn_s_setprio(0);
    }

    // ---- keys 32..63 (K rows 32+l31) ----
    {
      f32x16 sA = zf, sB = zf;
      __builtin_amdgcn_s_setprio(1);
#pragma unroll
      for (int db = 0; db < 4; ++db) {
        s16x8 kf = *(const s16x8*)&Kc[(32 + l31) * 64 + (((db * 2 + hi) ^ sw1) << 3)];
        sA = MFMA32(kf, qfA[db], sA);
        sB = MFMA32(kf, qfB[db], sB);
      }
      __builtin_amdgcn_s_setprio(0);
#pragma unroll
      for (int r = 0; r < 16; ++r) {
        sA[r] = ex2(sA[r]);
        sB[r] = ex2(sB[r]);
      }
      s16x8 pfA2, pfA3, pfB2, pfB3;
      PACK_PF(pfA2, sA, 0)
      PACK_PF(pfA3, sA, 8)
      PACK_PF(pfB2, sB, 0)
      PACK_PF(pfB3, sB, 8)
      LSUM_TREE(lsumA, sA)
      LSUM_TREE(lsumB, sB)
      __builtin_amdgcn_s_setprio(1);
      s16x8 v2 = *(const s16x8*)&Vc[l31 * 64 + (((4 + hi) ^ sw0) << 3)];
      s16x8 v3 = *(const s16x8*)&Vc[l31 * 64 + (((6 + hi) ^ sw0) << 3)];
      s16x8 w2 = *(const s16x8*)&Vc[(32 + l31) * 64 + (((4 + hi) ^ sw1) << 3)];
      s16x8 w3 = *(const s16x8*)&Vc[(32 + l31) * 64 + (((6 + hi) ^ sw1) << 3)];
      oA0 = MFMA32(v2, pfA2, oA0);
      oA0 = MFMA32(v3, pfA3, oA0);
      oA1 = MFMA32(w2, pfA2, oA1);
      oA1 = MFMA32(w3, pfA3, oA1);
      oB0 = MFMA32(v2, pfB2, oB0);
      oB0 = MFMA32(v3, pfB3, oB0);
      oB1 = MFMA32(w2, pfB2, oB1);
      oB1 = MFMA32(w3, pfB3, oB1);
      __builtin_amdgcn_s_setprio(0);
    }

    if (t < TKV - 1) {
      // wait only for tile t+1's 4 loads (t+2's 4 remain in flight)
      if (t + 2 < TKV) {
        asm volatile("s_waitcnt vmcnt(4)" ::: "memory");
      } else {
        asm volatile("s_waitcnt vmcnt(0)" ::: "memory");
      }
      __builtin_amdgcn_s_barrier();
      __builtin_amdgcn_sched_barrier(0);
      const int tmp = oc;
      oc = on;
      on = of;
      of = tmp;
    }
  }
#undef LSUM_TREE
#undef PACK_PF

  // bf16 partials: Opart[sz][bh][d][4096], Lpart[sz][bh][4096]
  const float lfullA = lsumA + __shfl_xor(lsumA, 32);
  const float lfullB = lsumB + __shfl_xor(lsumB, 32);
  const int qA = qbase + l31, qB = qbase + 32 + l31;
  const size_t ob = ((size_t)(sz * 24 + bh)) * 64 * 4096;
#pragma unroll
  for (int r = 0; r < 16; ++r) {
    const int dd = (r & 3) + 8 * (r >> 2) + 4 * hi;
    Opart[ob + (size_t)dd * 4096 + qA] = (unsigned short)f2bf(oA0[r]);
    Opart[ob + (size_t)(dd + 32) * 4096 + qA] = (unsigned short)f2bf(oA1[r]);
    Opart[ob + (size_t)dd * 4096 + qB] = (unsigned short)f2bf(oB0[r]);
    Opart[ob + (size_t)(dd + 32) * 4096 + qB] = (unsigned short)f2bf(oB1[r]);
  }
  Lpart[(size_t)(sz * 24 + bh) * 4096 + qA] = lfullA;
  Lpart[(size_t)(sz * 24 + bh) * 4096 + qB] = lfullB;
}

// Combine: O = sum_s Opart (bf16), l = sum_s Lpart; normalize; transpose -> bf16
__global__ __launch_bounds__(256) void attn_combine(
    const unsigned short* __restrict__ Opart, const float* __restrict__ Lpart,
    unsigned short* __restrict__ Aout) {
  __shared__ float T[64][65];
  const int q0 = blockIdx.x * 64, bh = blockIdx.y;
  const int t = threadIdx.x;
  const int d = t >> 2, qc = (t & 3) * 16;
  const size_t b0 = ((size_t)bh * 64 + d) * 4096 + q0 + qc;
  const size_t b1 = ((size_t)(24 + bh) * 64 + d) * 4096 + q0 + qc;
  s16x8 a0 = *(const s16x8*)&Opart[b0];
  s16x8 a1 = *(const s16x8*)&Opart[b0 + 8];
  s16x8 c0 = *(const s16x8*)&Opart[b1];
  s16x8 c1 = *(const s16x8*)&Opart[b1 + 8];
#pragma unroll
  for (int e = 0; e < 8; ++e) {
    T[qc + e][d] = bf2f((unsigned short)a0[e]) + bf2f((unsigned short)c0[e]);
    T[qc + 8 + e][d] = bf2f((unsigned short)a1[e]) + bf2f((unsigned short)c1[e]);
  }
  __syncthreads();
  const int q = t >> 2, dc = (t & 3) * 16;
  const float l = Lpart[(size_t)bh * 4096 + q0 + q] +
                  Lpart[(size_t)(24 + bh) * 4096 + q0 + q];
  const float inv = 1.0f / l;
  const int b = bh / 12, h = bh - b * 12;
  s16x8 o0, o1;
#pragma unroll
  for (int e = 0; e < 8; ++e) o0[e] = f2bf(T[q][dc + e] * inv);
#pragma unroll
  for (int e = 0; e < 8; ++e) o1[e] = f2bf(T[q][dc + 8 + e] * inv);
  const size_t gb = ((size_t)(b * 4096 + q0 + q)) * 768 + h * 64 + dc;
  *(s16x8*)&Aout[gb] = o0;
  *(s16x8*)&Aout[gb + 8] = o1;
}

// ---------------------------------------------------------------------------
// out = attn @ W_proj + b_proj  (global_load_lds staging, validated r9)
// ---------------------------------------------------------------------------
__global__ __launch_bounds__(256) void proj_gemm(
    const unsigned short* __restrict__ A, const unsigned short* __restrict__ Wt,
    const float* __restrict__ bias, float* __restrict__ out) {
  __shared__ __align__(16) short As[128 * 32];
  __shared__ __align__(16) short Bs[128 * 32];
  const int m0 = blockIdx.x * 128, n0 = blockIdx.y * 128;
  const int tid = threadIdx.x, lane = tid & 63, wid = tid >> 6;
  const int wr = wid >> 1, wc = wid & 1;
  const int lr = lane & 15, s4 = lane >> 4;

  const int crow = lane >> 2;
  const int ccol = (lane & 3) ^ (crow & 3);
  const unsigned short* ga0 = A + (size_t)(m0 + wid * 32 + crow) * 768 + ccol * 8;
  const unsigned short* ga1 = ga0 + (size_t)16 * 768;
  const unsigned short* gb0 = Wt + (size_t)(n0 + wid * 32 + crow) * 768 + ccol * 8;
  const unsigned short* gb1 = gb0 + (size_t)16 * 768;
  short* lA0 = &As[(wid * 2) * 512];
  short* lA1 = &As[(wid * 2 + 1) * 512];
  short* lB0 = &Bs[(wid * 2) * 512];
  short* lB1 = &Bs[(wid * 2 + 1) * 512];

  f32x4 acc[4][4];
#pragma unroll
  for (int i = 0; i < 4; ++i)
#pragma unroll
    for (int j = 0; j < 4; ++j)
#pragma unroll
      for (int e = 0; e < 4; ++e) acc[i][j][e] = 0.f;

  for (int k0 = 0; k0 < 768; k0 += 32) {
    gl_lds16(ga0 + k0, lA0);
    gl_lds16(ga1 + k0, lA1);
    gl_lds16(gb0 + k0, lB0);
    gl_lds16(gb1 + k0, lB1);
    __syncthreads();
    s16x8 af[4], bfr[4];
#pragma unroll
    for (int mi = 0; mi < 4; ++mi) {
      const int row = wr * 64 + mi * 16 + lr;
      af[mi] = *(const s16x8*)&As[row * 32 + ((s4 ^ (row & 3)) << 3)];
    }
#pragma unroll
    for (int ni = 0; ni < 4; ++ni) {
      const int row = wc * 64 + ni * 16 + lr;
      bfr[ni] = *(const s16x8*)&Bs[row * 32 + ((s4 ^ (row & 3)) << 3)];
    }
#pragma unroll
    for (int mi = 0; mi < 4; ++mi)
#pragma unroll
      for (int ni = 0; ni < 4; ++ni)
        acc[mi][ni] = MFMA16(af[mi], bfr[ni], acc[mi][ni]);
    __syncthreads();
  }

  const int rbase = m0 + wr * 64 + (lane >> 4) * 4;
#pragma unroll
  for (int ni = 0; ni < 4; ++ni) {
    const int cb = n0 + wc * 64 + ni * 16;
    const float bi = bias[cb + lr];
#pragma unroll
    for (int mi = 0; mi < 4; ++mi) {
#pragma unroll
      for (int j = 0; j < 4; ++j) {
        const int row = rbase + mi * 16 + j;
        out[(size_t)row * 768 + cb + lr] = acc[mi][ni][j] + bi;
      }
    }
  }
}

extern "C" void kernel_launch(void* const* d_in, const int* in_sizes, int n_in,
                              void* d_out, int out_size, void* d_ws, size_t ws_size,
                              hipStream_t stream) {
  const float* x = (const float*)d_in[0];
  const float* W_qkv = (const float*)d_in[1];
  const float* b_qkv = (const float*)d_in[2];
  const float* W_proj = (const float*)d_in[3];
  const float* b_proj = (const float*)d_in[4];
  float* out = (float*)d_out;

  unsigned short* ws = (unsigned short*)d_ws;
  const size_t NQ = (size_t)24 * 4096 * 64;
  unsigned short* q = ws;
  unsigned short* k = ws + NQ;
  unsigned short* vt = ws + 2 * NQ;
  unsigned short* xb_attn = ws + 3 * NQ;  // Xb bf16, later attn out (aliased)
  unsigned short* wqt = ws + 4 * NQ;
  unsigned short* wpt = wqt + (size_t)2304 * 768;

  const size_t base_bytes = (4 * NQ + (size_t)2304 * 768 + (size_t)768 * 768) * 2;
  const size_t opart_bytes = (size_t)2 * 24 * 64 * 4096 * 2;  // bf16
  unsigned short* Opart = (unsigned short*)((char*)d_ws + base_bytes);
  float* Lpart = (float*)((char*)d_ws + base_bytes + opart_bytes);

  convert_x<<<3072, 256, 0, stream>>>(x, xb_attn);
  tconv<<<dim3(12, 36), 256, 0, stream>>>(W_qkv, wqt, 768, 2304);
  tconv<<<dim3(12, 12), 256, 0, stream>>>(W_proj, wpt, 768, 768);
  qkv_gemm<<<dim3(64, 18), 256, 0, stream>>>(xb_attn, wqt, b_qkv, q, k, vt);
  attn_fwd<<<768, 256, 0, stream>>>(q, k, vt, Opart, Lpart);
  attn_combine<<<dim3(64, 24), 256, 0, stream>>>(Opart, Lpart, xb_attn);
  proj_gemm<<<dim3(64, 6), 256, 0, stream>>>(xb_attn, wpt, b_proj, out);
}

// Round 20
// 223.771 us; speedup vs baseline: 1.0292x; 1.0143x over previous
//
#include <hip/hip_runtime.h>
#include <hip/hip_bf16.h>

typedef __attribute__((ext_vector_type(4))) float f32x4;
typedef __attribute__((ext_vector_type(16))) float f32x16;
typedef __attribute__((ext_vector_type(8))) short s16x8;
typedef __attribute__((ext_vector_type(4))) unsigned int u32x4;

#define MFMA16(a, b, c) __builtin_amdgcn_mfma_f32_16x16x32_bf16(a, b, c, 0, 0, 0)
#define MFMA32(a, b, c) __builtin_amdgcn_mfma_f32_32x32x16_bf16(a, b, c, 0, 0, 0)

__device__ __forceinline__ short f2bf(float f) {
  unsigned u = __builtin_bit_cast(unsigned, f);
  u += 0x7fffu + ((u >> 16) & 1u);
  return (short)(u >> 16);
}
__device__ __forceinline__ float bf2f(unsigned short u) {
  return __builtin_bit_cast(float, ((unsigned)u) << 16);
}
__device__ __forceinline__ unsigned cvtpk(float lo, float hi) {
  unsigned r;
  asm("v_cvt_pk_bf16_f32 %0, %1, %2" : "=v"(r) : "v"(lo), "v"(hi));
  return r;
}
__device__ __forceinline__ float ex2(float x) {
  float r;
  asm("v_exp_f32 %0, %1" : "=v"(r) : "v"(x));
  return r;
}
// async global->LDS, 16B per lane; LDS dest = wave-uniform base + lane*16
__device__ __forceinline__ void gl_lds16(const unsigned short* g, short* l) {
  __builtin_amdgcn_global_load_lds(
      (const __attribute__((address_space(1))) unsigned int*)g,
      (__attribute__((address_space(3))) unsigned int*)l, 16, 0, 0);
}

// ---------------------------------------------------------------------------
// Merged prep: X->bf16 (blocks 0..3071), W_qkv transpose (3072..3503),
// W_proj transpose (3504..3647). Bodies identical to validated r6-r19
// convert_x / tconv; branch is block-uniform so barriers are safe.
// ---------------------------------------------------------------------------
__global__ __launch_bounds__(256) void prep(
    const float* __restrict__ X, unsigned short* __restrict__ Xb,
    const float* __restrict__ Wq, unsigned short* __restrict__ Wqt,
    const float* __restrict__ Wp, unsigned short* __restrict__ Wpt) {
  __shared__ float T[64][65];
  const int bid = blockIdx.x;
  const int t = threadIdx.x;
  if (bid < 3072) {
    const size_t i = ((size_t)bid * 256 + t) * 8;
    f32x4 a = *(const f32x4*)(X + i);
    f32x4 b = *(const f32x4*)(X + i + 4);
    s16x8 o;
#pragma unroll
    for (int e = 0; e < 4; ++e) o[e] = f2bf(a[e]);
#pragma unroll
    for (int e = 0; e < 4; ++e) o[4 + e] = f2bf(b[e]);
    *(s16x8*)(Xb + i) = o;
    return;
  }
  const float* W;
  unsigned short* Wt;
  int N, rb;
  if (bid < 3504) {
    W = Wq; Wt = Wqt; N = 2304; rb = bid - 3072;
  } else {
    W = Wp; Wt = Wpt; N = 768; rb = bid - 3504;
  }
  const int k0 = (rb % 12) * 64, n0 = (rb / 12) * 64;
  const int tr = t >> 4, tc = (t & 15) * 4;
#pragma unroll
  for (int i = 0; i < 4; ++i) {
    f32x4 v = *(const f32x4*)&W[(size_t)(k0 + tr + i * 16) * N + n0 + tc];
#pragma unroll
    for (int e = 0; e < 4; ++e) T[tc + e][tr + i * 16] = v[e];
  }
  __syncthreads();
  const int nn = t >> 2, kk = (t & 3) * 16;
  s16x8 o0, o1;
#pragma unroll
  for (int j = 0; j < 8; ++j) o0[j] = f2bf(T[nn][kk + j]);
#pragma unroll
  for (int j = 0; j < 8; ++j) o1[j] = f2bf(T[nn][kk + 8 + j]);
  *(s16x8*)&Wt[(size_t)(n0 + nn) * 768 + k0 + kk] = o0;
  *(s16x8*)&Wt[(size_t)(n0 + nn) * 768 + k0 + kk + 8] = o1;
}

// ---------------------------------------------------------------------------
// GEMM tiles: 128x128, BK=32, 4 waves (2x2), global_load_lds staging.
// V store key-permuted (quad-swap within 16-token groups) — validated r12.
// ---------------------------------------------------------------------------
__global__ __launch_bounds__(256) void qkv_gemm(
    const unsigned short* __restrict__ Xb, const unsigned short* __restrict__ Wt,
    const float* __restrict__ bias, unsigned short* __restrict__ Qo,
    unsigned short* __restrict__ Ko, unsigned short* __restrict__ VTo) {
  __shared__ __align__(16) short As[128 * 32];
  __shared__ __align__(16) short Bs[128 * 32];
  const int m0 = blockIdx.x * 128, n0 = blockIdx.y * 128;
  const int tid = threadIdx.x, lane = tid & 63, wid = tid >> 6;
  const int wr = wid >> 1, wc = wid & 1;
  const int lr = lane & 15, s4 = lane >> 4;

  const int crow = lane >> 2;
  const int ccol = (lane & 3) ^ (crow & 3);
  const unsigned short* ga0 = Xb + (size_t)(m0 + wid * 32 + crow) * 768 + ccol * 8;
  const unsigned short* ga1 = ga0 + (size_t)16 * 768;
  const unsigned short* gb0 = Wt + (size_t)(n0 + wid * 32 + crow) * 768 + ccol * 8;
  const unsigned short* gb1 = gb0 + (size_t)16 * 768;
  short* lA0 = &As[(wid * 2) * 512];
  short* lA1 = &As[(wid * 2 + 1) * 512];
  short* lB0 = &Bs[(wid * 2) * 512];
  short* lB1 = &Bs[(wid * 2 + 1) * 512];

  f32x4 acc[4][4];
#pragma unroll
  for (int i = 0; i < 4; ++i)
#pragma unroll
    for (int j = 0; j < 4; ++j)
#pragma unroll
      for (int e = 0; e < 4; ++e) acc[i][j][e] = 0.f;

  for (int k0 = 0; k0 < 768; k0 += 32) {
    gl_lds16(ga0 + k0, lA0);
    gl_lds16(ga1 + k0, lA1);
    gl_lds16(gb0 + k0, lB0);
    gl_lds16(gb1 + k0, lB1);
    __syncthreads();
    s16x8 af[4], bfr[4];
#pragma unroll
    for (int mi = 0; mi < 4; ++mi) {
      const int row = wr * 64 + mi * 16 + lr;
      af[mi] = *(const s16x8*)&As[row * 32 + ((s4 ^ (row & 3)) << 3)];
    }
#pragma unroll
    for (int ni = 0; ni < 4; ++ni) {
      const int row = wc * 64 + ni * 16 + lr;
      bfr[ni] = *(const s16x8*)&Bs[row * 32 + ((s4 ^ (row & 3)) << 3)];
    }
#pragma unroll
    for (int mi = 0; mi < 4; ++mi)
#pragma unroll
      for (int ni = 0; ni < 4; ++ni)
        acc[mi][ni] = MFMA16(af[mi], bfr[ni], acc[mi][ni]);
    __syncthreads();
  }

  const float QSC = 0.18033688011f;  // 0.125 * log2(e)
  const int lg = lane >> 4;
  const int plg = ((lg & 1) << 1) | ((lg >> 1) & 1);  // quad swap 1<->2
  const int rbase = m0 + wr * 64 + lg * 4;
#pragma unroll
  for (int ni = 0; ni < 4; ++ni) {
    const int cb = n0 + wc * 64 + ni * 16;
    const int which = cb / 768;
    const int rem = cb - which * 768;
    const int h = rem >> 6;
    const int d = (rem & 63) + lr;
    const float bi = bias[cb + lr];
#pragma unroll
    for (int mi = 0; mi < 4; ++mi) {
#pragma unroll
      for (int j = 0; j < 4; ++j) {
        const int row = rbase + mi * 16 + j;
        const int bb = row >> 12, t = row & 4095;
        const float v = acc[mi][ni][j] + bi;
        const size_t hb = (size_t)(bb * 12 + h);
        if (which == 0)
          Qo[(hb * 4096 + t) * 64 + d] = (unsigned short)f2bf(v * QSC);
        else if (which == 1)
          Ko[(hb * 4096 + t) * 64 + d] = (unsigned short)f2bf(v);
        else {
          const int tp = (t & ~15) + plg * 4 + j;  // key-permuted token slot
          VTo[(hb * 64 + d) * 4096 + tp] = (unsigned short)f2bf(v);
        }
      }
    }
  }
}

// ---------------------------------------------------------------------------
// Flash attention (r17-validated, session best): dual-q-subtile 64 q/wave,
// gl_lds staging, VALU lsum tree, KV-split-2, bf16 partials, XCD swizzle.
// ---------------------------------------------------------------------------
#define TKV 32

__global__ __launch_bounds__(256) void attn_fwd(
    const unsigned short* __restrict__ Qg, const unsigned short* __restrict__ Kg,
    const unsigned short* __restrict__ VTg,
    unsigned short* __restrict__ Opart, float* __restrict__ Lpart) {
  __shared__ __align__(16) short smem[16384];  // [K0|K1|V0|V1] 4096 shorts each
  const int lin = blockIdx.x;
  const int wg = (lin & 7) * 96 + (lin >> 3);  // 768 = 8*96, bijective
  const int qt = wg & 15, bh = (wg >> 4) % 24, sz = wg / 384;
  const int tok0 = sz * TKV * 64;
  const unsigned short* Qh = Qg + (size_t)bh * 4096 * 64;
  const unsigned short* Kh = Kg + (size_t)bh * 4096 * 64;
  const unsigned short* Vh = VTg + (size_t)bh * 4096 * 64;  // [d][tok], permuted
  const int tid = threadIdx.x, lane = tid & 63, wid = tid >> 6;
  const int l31 = lane & 31, hi = lane >> 5;
  const int sw0 = (l31 + (l31 >> 3)) & 7;
  const int sw1 = (sw0 + 4) & 7;
  const int qbase = qt * 256 + wid * 64;

  s16x8 qfA[4], qfB[4];
#pragma unroll
  for (int db = 0; db < 4; ++db) {
    qfA[db] = *(const s16x8*)&Qh[(size_t)(qbase + l31) * 64 + db * 16 + hi * 8];
    qfB[db] = *(const s16x8*)&Qh[(size_t)(qbase + 32 + l31) * 64 + db * 16 + hi * 8];
  }

  f32x16 zf;
#pragma unroll
  for (int r = 0; r < 16; ++r) zf[r] = 0.f;
  f32x16 oA0 = zf, oA1 = zf, oB0 = zf, oB1 = zf;
  float lsumA = 0.f, lsumB = 0.f;

  const int r0 = wid * 16 + (lane >> 3);
  const int r1 = r0 + 8;
  const int c16 = lane & 7;
  const int sc0 = (c16 ^ ((r0 + (r0 >> 3)) & 7)) << 3;
  const int sc1 = (c16 ^ ((r1 + (r1 >> 3)) & 7)) << 3;
  const unsigned short* kg0 = Kh + (size_t)(tok0 + r0) * 64 + sc0;  // + t*4096
  const unsigned short* kg1 = Kh + (size_t)(tok0 + r1) * 64 + sc1;
  const unsigned short* vg0 = Vh + (size_t)r0 * 4096 + tok0 + sc0;  // + t*64
  const unsigned short* vg1 = Vh + (size_t)r1 * 4096 + tok0 + sc1;
  short* const ldsK0 = &smem[(wid * 2) * 512];
  short* const ldsK1 = &smem[(wid * 2 + 1) * 512];
  short* const ldsV0 = &smem[8192 + (wid * 2) * 512];
  short* const ldsV1 = &smem[8192 + (wid * 2 + 1) * 512];

  gl_lds16(kg0, ldsK0);
  gl_lds16(kg1, ldsK1);
  gl_lds16(vg0, ldsV0);
  gl_lds16(vg1, ldsV1);
  __syncthreads();

#define PACK_PF(pfv, sv, bse)                                           \
  {                                                                     \
    u32x4 fw;                                                           \
    fw[0] = cvtpk(sv[bse + 0], sv[bse + 1]);                            \
    fw[1] = cvtpk(sv[bse + 2], sv[bse + 3]);                            \
    fw[2] = cvtpk(sv[bse + 4], sv[bse + 5]);                            \
    fw[3] = cvtpk(sv[bse + 6], sv[bse + 7]);                            \
    pfv = __builtin_bit_cast(s16x8, fw);                                \
  }
#define LSUM_TREE(lsum, sv)                                             \
  {                                                                     \
    float ta[8];                                                        \
    _Pragma("unroll") for (int r = 0; r < 8; ++r) ta[r] = sv[r] + sv[r + 8]; \
    _Pragma("unroll") for (int off = 4; off; off >>= 1)                 \
      _Pragma("unroll") for (int r = 0; r < off; ++r) ta[r] += ta[r + off]; \
    lsum += ta[0];                                                      \
  }

  int cur = 0;
  for (int t = 0; t < TKV; ++t) {
    if (t < TKV - 1) {
      const int nb = (cur ^ 1) * 4096;
      gl_lds16(kg0 + (size_t)(t + 1) * 4096, ldsK0 + nb);
      gl_lds16(kg1 + (size_t)(t + 1) * 4096, ldsK1 + nb);
      gl_lds16(vg0 + (t + 1) * 64, ldsV0 + nb);
      gl_lds16(vg1 + (t + 1) * 64, ldsV1 + nb);
    }
    const short* Kc = smem + cur * 4096;
    const short* Vc = smem + 8192 + cur * 4096;

    // ---- keys 0..31 (K rows l31) ----
    {
      f32x16 sA = zf, sB = zf;
      __builtin_amdgcn_s_setprio(1);
#pragma unroll
      for (int db = 0; db < 4; ++db) {
        s16x8 kf = *(const s16x8*)&Kc[l31 * 64 + (((db * 2 + hi) ^ sw0) << 3)];
        sA = MFMA32(kf, qfA[db], sA);
        sB = MFMA32(kf, qfB[db], sB);
      }
      __builtin_amdgcn_s_setprio(0);
#pragma unroll
      for (int r = 0; r < 16; ++r) {
        sA[r] = ex2(sA[r]);
        sB[r] = ex2(sB[r]);
      }
      s16x8 pfA0, pfA1, pfB0, pfB1;
      PACK_PF(pfA0, sA, 0)
      PACK_PF(pfA1, sA, 8)
      PACK_PF(pfB0, sB, 0)
      PACK_PF(pfB1, sB, 8)
      LSUM_TREE(lsumA, sA)
      LSUM_TREE(lsumB, sB)
      __builtin_amdgcn_s_setprio(1);
      s16x8 v0 = *(const s16x8*)&Vc[l31 * 64 + (((0 + hi) ^ sw0) << 3)];
      s16x8 v1 = *(const s16x8*)&Vc[l31 * 64 + (((2 + hi) ^ sw0) << 3)];
      s16x8 w0 = *(const s16x8*)&Vc[(32 + l31) * 64 + (((0 + hi) ^ sw1) << 3)];
      s16x8 w1 = *(const s16x8*)&Vc[(32 + l31) * 64 + (((2 + hi) ^ sw1) << 3)];
      oA0 = MFMA32(v0, pfA0, oA0);
      oA0 = MFMA32(v1, pfA1, oA0);
      oA1 = MFMA32(w0, pfA0, oA1);
      oA1 = MFMA32(w1, pfA1, oA1);
      oB0 = MFMA32(v0, pfB0, oB0);
      oB0 = MFMA32(v1, pfB1, oB0);
      oB1 = MFMA32(w0, pfB0, oB1);
      oB1 = MFMA32(w1, pfB1, oB1);
      __builtin_amdgcn_s_setprio(0);
    }

    // ---- keys 32..63 (K rows 32+l31) ----
    {
      f32x16 sA = zf, sB = zf;
      __builtin_amdgcn_s_setprio(1);
#pragma unroll
      for (int db = 0; db < 4; ++db) {
        s16x8 kf = *(const s16x8*)&Kc[(32 + l31) * 64 + (((db * 2 + hi) ^ sw1) << 3)];
        sA = MFMA32(kf, qfA[db], sA);
        sB = MFMA32(kf, qfB[db], sB);
      }
      __builtin_amdgcn_s_setprio(0);
#pragma unroll
      for (int r = 0; r < 16; ++r) {
        sA[r] = ex2(sA[r]);
        sB[r] = ex2(sB[r]);
      }
      s16x8 pfA2, pfA3, pfB2, pfB3;
      PACK_PF(pfA2, sA, 0)
      PACK_PF(pfA3, sA, 8)
      PACK_PF(pfB2, sB, 0)
      PACK_PF(pfB3, sB, 8)
      LSUM_TREE(lsumA, sA)
      LSUM_TREE(lsumB, sB)
      __builtin_amdgcn_s_setprio(1);
      s16x8 v2 = *(const s16x8*)&Vc[l31 * 64 + (((4 + hi) ^ sw0) << 3)];
      s16x8 v3 = *(const s16x8*)&Vc[l31 * 64 + (((6 + hi) ^ sw0) << 3)];
      s16x8 w2 = *(const s16x8*)&Vc[(32 + l31) * 64 + (((4 + hi) ^ sw1) << 3)];
      s16x8 w3 = *(const s16x8*)&Vc[(32 + l31) * 64 + (((6 + hi) ^ sw1) << 3)];
      oA0 = MFMA32(v2, pfA2, oA0);
      oA0 = MFMA32(v3, pfA3, oA0);
      oA1 = MFMA32(w2, pfA2, oA1);
      oA1 = MFMA32(w3, pfA3, oA1);
      oB0 = MFMA32(v2, pfB2, oB0);
      oB0 = MFMA32(v3, pfB3, oB0);
      oB1 = MFMA32(w2, pfB2, oB1);
      oB1 = MFMA32(w3, pfB3, oB1);
      __builtin_amdgcn_s_setprio(0);
    }

    if (t < TKV - 1) {
      __syncthreads();  // drains vmcnt -> tile t+1 resident
      cur ^= 1;
    }
  }
#undef LSUM_TREE
#undef PACK_PF

  // bf16 partials: Opart[sz][bh][d][4096], Lpart[sz][bh][4096]
  const float lfullA = lsumA + __shfl_xor(lsumA, 32);
  const float lfullB = lsumB + __shfl_xor(lsumB, 32);
  const int qA = qbase + l31, qB = qbase + 32 + l31;
  const size_t ob = ((size_t)(sz * 24 + bh)) * 64 * 4096;
#pragma unroll
  for (int r = 0; r < 16; ++r) {
    const int dd = (r & 3) + 8 * (r >> 2) + 4 * hi;
    Opart[ob + (size_t)dd * 4096 + qA] = (unsigned short)f2bf(oA0[r]);
    Opart[ob + (size_t)(dd + 32) * 4096 + qA] = (unsigned short)f2bf(oA1[r]);
    Opart[ob + (size_t)dd * 4096 + qB] = (unsigned short)f2bf(oB0[r]);
    Opart[ob + (size_t)(dd + 32) * 4096 + qB] = (unsigned short)f2bf(oB1[r]);
  }
  Lpart[(size_t)(sz * 24 + bh) * 4096 + qA] = lfullA;
  Lpart[(size_t)(sz * 24 + bh) * 4096 + qB] = lfullB;
}

// Combine: O = sum_s Opart (bf16), l = sum_s Lpart; normalize; transpose -> bf16
__global__ __launch_bounds__(256) void attn_combine(
    const unsigned short* __restrict__ Opart, const float* __restrict__ Lpart,
    unsigned short* __restrict__ Aout) {
  __shared__ float T[64][65];
  const int q0 = blockIdx.x * 64, bh = blockIdx.y;
  const int t = threadIdx.x;
  const int d = t >> 2, qc = (t & 3) * 16;
  const size_t b0 = ((size_t)bh * 64 + d) * 4096 + q0 + qc;
  const size_t b1 = ((size_t)(24 + bh) * 64 + d) * 4096 + q0 + qc;
  s16x8 a0 = *(const s16x8*)&Opart[b0];
  s16x8 a1 = *(const s16x8*)&Opart[b0 + 8];
  s16x8 c0 = *(const s16x8*)&Opart[b1];
  s16x8 c1 = *(const s16x8*)&Opart[b1 + 8];
#pragma unroll
  for (int e = 0; e < 8; ++e) {
    T[qc + e][d] = bf2f((unsigned short)a0[e]) + bf2f((unsigned short)c0[e]);
    T[qc + 8 + e][d] = bf2f((unsigned short)a1[e]) + bf2f((unsigned short)c1[e]);
  }
  __syncthreads();
  const int q = t >> 2, dc = (t & 3) * 16;
  const float l = Lpart[(size_t)bh * 4096 + q0 + q] +
                  Lpart[(size_t)(24 + bh) * 4096 + q0 + q];
  const float inv = 1.0f / l;
  const int b = bh / 12, h = bh - b * 12;
  s16x8 o0, o1;
#pragma unroll
  for (int e = 0; e < 8; ++e) o0[e] = f2bf(T[q][dc + e] * inv);
#pragma unroll
  for (int e = 0; e < 8; ++e) o1[e] = f2bf(T[q][dc + 8 + e] * inv);
  const size_t gb = ((size_t)(b * 4096 + q0 + q)) * 768 + h * 64 + dc;
  *(s16x8*)&Aout[gb] = o0;
  *(s16x8*)&Aout[gb + 8] = o1;
}

// ---------------------------------------------------------------------------
// out = attn @ W_proj + b_proj  (global_load_lds staging, validated r9)
// ---------------------------------------------------------------------------
__global__ __launch_bounds__(256) void proj_gemm(
    const unsigned short* __restrict__ A, const unsigned short* __restrict__ Wt,
    const float* __restrict__ bias, float* __restrict__ out) {
  __shared__ __align__(16) short As[128 * 32];
  __shared__ __align__(16) short Bs[128 * 32];
  const int m0 = blockIdx.x * 128, n0 = blockIdx.y * 128;
  const int tid = threadIdx.x, lane = tid & 63, wid = tid >> 6;
  const int wr = wid >> 1, wc = wid & 1;
  const int lr = lane & 15, s4 = lane >> 4;

  const int crow = lane >> 2;
  const int ccol = (lane & 3) ^ (crow & 3);
  const unsigned short* ga0 = A + (size_t)(m0 + wid * 32 + crow) * 768 + ccol * 8;
  const unsigned short* ga1 = ga0 + (size_t)16 * 768;
  const unsigned short* gb0 = Wt + (size_t)(n0 + wid * 32 + crow) * 768 + ccol * 8;
  const unsigned short* gb1 = gb0 + (size_t)16 * 768;
  short* lA0 = &As[(wid * 2) * 512];
  short* lA1 = &As[(wid * 2 + 1) * 512];
  short* lB0 = &Bs[(wid * 2) * 512];
  short* lB1 = &Bs[(wid * 2 + 1) * 512];

  f32x4 acc[4][4];
#pragma unroll
  for (int i = 0; i < 4; ++i)
#pragma unroll
    for (int j = 0; j < 4; ++j)
#pragma unroll
      for (int e = 0; e < 4; ++e) acc[i][j][e] = 0.f;

  for (int k0 = 0; k0 < 768; k0 += 32) {
    gl_lds16(ga0 + k0, lA0);
    gl_lds16(ga1 + k0, lA1);
    gl_lds16(gb0 + k0, lB0);
    gl_lds16(gb1 + k0, lB1);
    __syncthreads();
    s16x8 af[4], bfr[4];
#pragma unroll
    for (int mi = 0; mi < 4; ++mi) {
      const int row = wr * 64 + mi * 16 + lr;
      af[mi] = *(const s16x8*)&As[row * 32 + ((s4 ^ (row & 3)) << 3)];
    }
#pragma unroll
    for (int ni = 0; ni < 4; ++ni) {
      const int row = wc * 64 + ni * 16 + lr;
      bfr[ni] = *(const s16x8*)&Bs[row * 32 + ((s4 ^ (row & 3)) << 3)];
    }
#pragma unroll
    for (int mi = 0; mi < 4; ++mi)
#pragma unroll
      for (int ni = 0; ni < 4; ++ni)
        acc[mi][ni] = MFMA16(af[mi], bfr[ni], acc[mi][ni]);
    __syncthreads();
  }

  const int rbase = m0 + wr * 64 + (lane >> 4) * 4;
#pragma unroll
  for (int ni = 0; ni < 4; ++ni) {
    const int cb = n0 + wc * 64 + ni * 16;
    const float bi = bias[cb + lr];
#pragma unroll
    for (int mi = 0; mi < 4; ++mi) {
#pragma unroll
      for (int j = 0; j < 4; ++j) {
        const int row = rbase + mi * 16 + j;
        out[(size_t)row * 768 + cb + lr] = acc[mi][ni][j] + bi;
      }
    }
  }
}

extern "C" void kernel_launch(void* const* d_in, const int* in_sizes, int n_in,
                              void* d_out, int out_size, void* d_ws, size_t ws_size,
                              hipStream_t stream) {
  const float* x = (const float*)d_in[0];
  const float* W_qkv = (const float*)d_in[1];
  const float* b_qkv = (const float*)d_in[2];
  const float* W_proj = (const float*)d_in[3];
  const float* b_proj = (const float*)d_in[4];
  float* out = (float*)d_out;

  unsigned short* ws = (unsigned short*)d_ws;
  const size_t NQ = (size_t)24 * 4096 * 64;
  unsigned short* q = ws;
  unsigned short* k = ws + NQ;
  unsigned short* vt = ws + 2 * NQ;
  unsigned short* xb_attn = ws + 3 * NQ;  // Xb bf16, later attn out (aliased)
  unsigned short* wqt = ws + 4 * NQ;
  unsigned short* wpt = wqt + (size_t)2304 * 768;

  const size_t base_bytes = (4 * NQ + (size_t)2304 * 768 + (size_t)768 * 768) * 2;
  const size_t opart_bytes = (size_t)2 * 24 * 64 * 4096 * 2;  // bf16
  unsigned short* Opart = (unsigned short*)((char*)d_ws + base_bytes);
  float* Lpart = (float*)((char*)d_ws + base_bytes + opart_bytes);

  prep<<<3648, 256, 0, stream>>>(x, xb_attn, W_qkv, wqt, W_proj, wpt);
  qkv_gemm<<<dim3(64, 18), 256, 0, stream>>>(xb_attn, wqt, b_qkv, q, k, vt);
  attn_fwd<<<768, 256, 0, stream>>>(q, k, vt, Opart, Lpart);
  attn_combine<<<dim3(64, 24), 256, 0, stream>>>(Opart, Lpart, xb_attn);
  proj_gemm<<<dim3(64, 6), 256, 0, stream>>>(xb_attn, wpt, b_proj, out);
}